// Round 2
// baseline (656.508 us; speedup 1.0000x reference)
//
#include <hip/hip_runtime.h>

// DGCN decomposition:
//   m = MLP(x[0])                       (tiny, fp32)
//   S = softmax(relu(E1 @ m @ E2^T))    (row softmax, fp32 -> bf16)
//   G1 = S @ X, G2 = S @ G1             (bf16 MFMA GEMMs, X = x as [m, (b,i,s)])
//   out[b,o,n,s] = bias[n,o] + sum_{k,i} Gk[n,(b,i,s)] * W[n,k,i,o]
// S^2 is never materialized (saves a 2048^3 GEMM).
//
// R5: k_gemm gets true T4 counted-vmcnt pipelining: per tile, issue next tile's
//   8 global_load_lds FIRST, then s_waitcnt vmcnt(8) (drains only the current
//   tile's loads; never 0 in main loop), then raw s_barrier gate. In-loop
//   __syncthreads removed (raw barriers only). Wrapped dummy STAGE on the last
//   tile keeps the vmcnt immediate constant; vmcnt(0) only before the epilogue
//   LDS reuse. Everything else unchanged from R4.

typedef float  f32x4  __attribute__((ext_vector_type(4)));
typedef __bf16 bf16x8 __attribute__((ext_vector_type(8)));
typedef unsigned short u16;

#define GLOAD16(gp, lp) __builtin_amdgcn_global_load_lds( \
    (const __attribute__((address_space(1))) void*)(gp),  \
    (__attribute__((address_space(3))) void*)(lp), 16, 0, 0)

__device__ __forceinline__ u16 f2bf(float f){
  union { float f; unsigned u; } v; v.f = f;
  unsigned u = v.u;
  u += 0x7fffu + ((u >> 16) & 1u);   // round-to-nearest-even
  return (u16)(u >> 16);
}
__device__ __forceinline__ float bf2f(u16 h){
  union { unsigned u; float f; } v; v.u = ((unsigned)h) << 16;
  return v.f;
}
// unpack one uint (2 packed bf16) -> float2 {lo, hi} (lo = lower address)
__device__ __forceinline__ float2 unp2(unsigned u){
  union { unsigned q; float f; } a, b;
  a.q = u << 16; b.q = u & 0xffff0000u;
  return make_float2(a.f, b.f);
}

// ---------------- K1: h1[i,n] = tanh(x[0,i,n,:] . fc0_w + fc0_b) ----------------
__global__ void k_h1(const float* __restrict__ x, const float* __restrict__ fc0w,
                     const float* __restrict__ fc0b, float* __restrict__ h1){
  int g = blockIdx.x * 256 + threadIdx.x;        // g = i*2048 + n, 65536 total
  const float* xp = x + (long)g * 12;
  float s = fc0b[0];
  #pragma unroll
  for (int j = 0; j < 12; j++) s += xp[j] * fc0w[j];
  h1[g] = tanhf(s);
}

// ---------------- K2a: h2raw[i*16+d] = sum_n h1[i,n]*fc1_w[d,n] ----------------
__global__ __launch_bounds__(256) void k_h2a(const float* __restrict__ h1,
                                             const float* __restrict__ fc1w,
                                             float* __restrict__ h2raw){
  __shared__ float red[4];
  int id = blockIdx.x;                 // 0..511 = i*16+d
  int i = id >> 4, d = id & 15;
  int t = threadIdx.x;
  const float* hp = h1 + i * 2048;
  const float* wp = fc1w + d * 2048;
  float s = 0.f;
  for (int nn = t; nn < 2048; nn += 256) s += hp[nn] * wp[nn];
  for (int off = 32; off > 0; off >>= 1) s += __shfl_down(s, off, 64);
  if ((t & 63) == 0) red[t >> 6] = s;
  __syncthreads();
  if (t == 0) h2raw[id] = red[0] + red[1] + red[2] + red[3];
}

// ---------------- K2b: h2 = tanh(h2raw + fc1_b); m[d,e] = tanh(sum_i h2[i,d]*fc2_w[e,i] + fc2_b[e]) ----------------
__global__ void k_h2b(const float* __restrict__ h2raw, const float* __restrict__ fc1b,
                      const float* __restrict__ fc2w, const float* __restrict__ fc2b,
                      float* __restrict__ mmat){
  __shared__ float h2[512];
  int t = threadIdx.x;                 // 512 threads
  {
    int d = t & 15;
    h2[t] = tanhf(h2raw[t] + fc1b[d]);
  }
  __syncthreads();
  if (t < 256){
    int dd = t >> 4, e = t & 15;
    float s2 = fc2b[e];
    #pragma unroll
    for (int ii = 0; ii < 32; ii++) s2 += h2[ii * 16 + dd] * fc2w[e * 32 + ii];
    mmat[dd * 16 + e] = tanhf(s2);
  }
}

// ---------------- K3: support row n = softmax_j(relu(sum_d' (E1[n]@m)[d'] * E2[j,d'])) -> bf16 ----------------
__global__ __launch_bounds__(256) void k_support(const float* __restrict__ E1,
                                                 const float* __restrict__ E2,
                                                 const float* __restrict__ mmat,
                                                 u16* __restrict__ sup){
  __shared__ float ml[256];
  __shared__ float tv[16];
  __shared__ float red[8];
  int n = blockIdx.x, t = threadIdx.x;
  ml[t] = mmat[t];
  __syncthreads();
  if (t < 16){
    float s = 0.f;
    const float* er = E1 + n * 16;
    #pragma unroll
    for (int d = 0; d < 16; d++) s += er[d] * ml[d * 16 + t];
    tv[t] = s;
  }
  __syncthreads();
  float lmax = -1e30f;
  float lv[8];
  #pragma unroll
  for (int p = 0; p < 8; p++){
    int j = t + p * 256;
    const float* e2 = E2 + j * 16;
    float s = 0.f;
    #pragma unroll
    for (int d = 0; d < 16; d++) s += tv[d] * e2[d];
    s = fmaxf(s, 0.f);                 // relu BEFORE softmax
    lv[p] = s;
    lmax = fmaxf(lmax, s);
  }
  for (int off = 32; off > 0; off >>= 1) lmax = fmaxf(lmax, __shfl_down(lmax, off, 64));
  if ((t & 63) == 0) red[t >> 6] = lmax;
  __syncthreads();
  if (t == 0) red[0] = fmaxf(fmaxf(red[0], red[1]), fmaxf(red[2], red[3]));
  __syncthreads();
  float mx = red[0];
  float lsum = 0.f;
  #pragma unroll
  for (int p = 0; p < 8; p++){ float e = __expf(lv[p] - mx); lv[p] = e; lsum += e; }
  for (int off = 32; off > 0; off >>= 1) lsum += __shfl_down(lsum, off, 64);
  if ((t & 63) == 0) red[4 + (t >> 6)] = lsum;
  __syncthreads();
  if (t == 0) red[4] = red[4] + red[5] + red[6] + red[7];
  __syncthreads();
  float inv = 1.f / red[4];
  #pragma unroll
  for (int p = 0; p < 8; p++) sup[(long)n * 2048 + t + p * 256] = f2bf(lv[p] * inv);
}

// ---------------- K4: fused Xb[m][c]=bf16(x), Xbt[c][m]=Xb[m][c] (reads x once) ----------------
__global__ __launch_bounds__(256) void k_xbt2(const float* __restrict__ x,
                                              u16* __restrict__ Xb,
                                              u16* __restrict__ Xbt){
  __shared__ u16 tile[64][65];
  int cT = blockIdx.x * 64;            // 192 tiles over 12288
  int mT = blockIdx.y * 64;            // 32 tiles over 2048
  int t = threadIdx.x;
  int r = t >> 6, cc = t & 63;
  int cg = cT + cc;
  int bi = cg / 12, s = cg - bi * 12;
  long xoff = (long)bi * 24576 + s;    // x[((bi)*2048 + m)*12 + s]
  #pragma unroll
  for (int p = 0; p < 16; p++){
    int rr = p * 4 + r;
    u16 v = f2bf(x[xoff + (long)(mT + rr) * 12]);
    tile[rr][cc] = v;
    Xb[(long)(mT + rr) * 12288 + cg] = v;
  }
  __syncthreads();
  #pragma unroll
  for (int p = 0; p < 16; p++){
    int rr = p * 4 + r;
    Xbt[(long)(cT + rr) * 2048 + mT + cc] = tile[cc][rr];
  }
}

// ---------------- K6: W[n,k,i,o] via float4 + L1 reuse (4 n per block share P slice) ----------------
__global__ __launch_bounds__(256) void k_wb2(const float* __restrict__ E1, const float* __restrict__ E2,
                                             const float* __restrict__ P1, const float* __restrict__ P2,
                                             const float* __restrict__ BP1, const float* __restrict__ BP2,
                                             float* __restrict__ W, float* __restrict__ biasN){
  int bid = blockIdx.x, t = threadIdx.x;
  if (bid < 6144){
    int nb = bid & 511, rb = bid >> 9;       // 512 n-blocks x 12 r-blocks
    int n = nb * 4 + (t >> 6);
    int r4 = rb * 64 + (t & 63);             // float4 index within 768
    const float* e1 = E1 + n * 16;
    const float* e2 = E2 + n * 16;
    f32x4 s = {0.f, 0.f, 0.f, 0.f};
    #pragma unroll
    for (int d = 0; d < 16; d++){
      f32x4 p1 = *(const f32x4*)(P1 + d * 3072 + r4 * 4);
      f32x4 p2 = *(const f32x4*)(P2 + d * 3072 + r4 * 4);
      s += p1 * e1[d] + p2 * e2[d];
    }
    *(f32x4*)(W + (long)n * 3072 + r4 * 4) = s;
  } else {
    int e = (bid - 6144) * 256 + t;          // 65536 bias outputs
    int n = e >> 5, o = e & 31;
    const float* e1 = E1 + n * 16;
    const float* e2 = E2 + n * 16;
    float s = 0.f;
    #pragma unroll
    for (int d = 0; d < 16; d++) s += e1[d] * BP1[d * 32 + o] + e2[d] * BP2[d * 32 + o];
    biasN[e] = s;
  }
}

// ---------------- GEMM: C[m][c] = sum_k A[m][k] * Bt[c][k]; 256x256 tile, 8 waves ----------------
// Phase-split schedule (4 phases/K-tile, 16 MFMA per barrier-pair), BK=64 double
// buffer, counted-vmcnt pipeline: STAGE(t+1) issued first each tile, then
// s_waitcnt vmcnt(8) (waits only tile t's loads; 8 stay in flight), s_barrier
// gate, phases. Never drains to 0 in the main loop (T4). LDS XOR swizzle as R4.
__global__ __launch_bounds__(512, 2) void k_gemm(const u16* __restrict__ A,
                                                 const u16* __restrict__ Bt,
                                                 u16* __restrict__ Cd,
                                                 u16* __restrict__ Ct,
                                                 int writeT){
  __shared__ u16 lds[65536];           // 128 KiB: buf0 A[0,16384) B[16384,32768); buf1 +32768
  int tid  = threadIdx.x;
  int wave = tid >> 6, lane = tid & 63;
  int l15 = lane & 15, q = lane >> 4, l7 = l15 & 7;
  int wm = wave >> 2, wn = wave & 3;   // 2 x 4 waves; wave-tile 128(m) x 64(c)

  // bijective XCD swizzle: 8 xcds x 48 slots; 6 consecutive slots share the A panel
  int lin  = blockIdx.y * 48 + blockIdx.x;   // 0..383
  int xcd  = lin & 7;
  int slot = lin >> 3;                 // 0..47
  int yN   = slot / 6;                 // 0..7   (m-tile)
  int xN   = (slot - yN * 6) * 8 + xcd;      // 0..47 (c-tile)
  long mBase = (long)yN * 256;
  long cBase = (long)xN * 256;

  f32x4 acc[8][4];
  #pragma unroll
  for (int t2 = 0; t2 < 8; t2++)
    #pragma unroll
    for (int u2 = 0; u2 < 4; u2++) acc[t2][u2] = (f32x4){0.f, 0.f, 0.f, 0.f};

  // staging: chunk L = j*512 + tid -> LDS (row = L>>3, c_lds = L&7); source chunk
  // is pre-swizzled: cel = (tid&7) ^ ((tid>>3)&7)  (row&7 == (tid>>3)&7 for all j)
  int Lrow = tid >> 3;
  int cel  = (tid & 7) ^ (Lrow & 7);
  const u16* gAp = A  + (mBase + Lrow) * 2048 + cel * 8;
  const u16* gBp = Bt + (cBase + Lrow) * 2048 + cel * 8;

#define STAGE_TILE(nx, ko) do { \
    GLOAD16(gAp + (ko),                  lds + (nx) +         wave * 512); \
    GLOAD16(gAp +  64 * 2048 + (ko),     lds + (nx) +  4096 + wave * 512); \
    GLOAD16(gAp + 128 * 2048 + (ko),     lds + (nx) +  8192 + wave * 512); \
    GLOAD16(gAp + 192 * 2048 + (ko),     lds + (nx) + 12288 + wave * 512); \
    GLOAD16(gBp + (ko),                  lds + (nx) + 16384 + wave * 512); \
    GLOAD16(gBp +  64 * 2048 + (ko),     lds + (nx) + 20480 + wave * 512); \
    GLOAD16(gBp + 128 * 2048 + (ko),     lds + (nx) + 24576 + wave * 512); \
    GLOAD16(gBp + 192 * 2048 + (ko),     lds + (nx) + 28672 + wave * 512); \
  } while(0)

#define LDA(dst, mq) do { \
    _Pragma("unroll") \
    for (int t2 = 0; t2 < 4; t2++){ \
      int row = wm * 128 + ((mq) * 4 + t2) * 16 + l15; \
      _Pragma("unroll") \
      for (int kk = 0; kk < 2; kk++) \
        dst[t2][kk] = *(const bf16x8*)&lds[bA + row * 64 + (((kk << 2) | q) ^ l7) * 8]; \
    } } while(0)

#define LDB(nq) do { \
    _Pragma("unroll") \
    for (int u2 = 0; u2 < 2; u2++){ \
      int row = wn * 64 + ((nq) * 2 + u2) * 16 + l15; \
      _Pragma("unroll") \
      for (int kk = 0; kk < 2; kk++) \
        bb[u2][kk] = *(const bf16x8*)&lds[bB + row * 64 + (((kk << 2) | q) ^ l7) * 8]; \
    } } while(0)

#define MFMA_Q(AF, mq, nq) do { \
    __builtin_amdgcn_s_setprio(1); \
    _Pragma("unroll") \
    for (int t2 = 0; t2 < 4; t2++) \
      _Pragma("unroll") \
      for (int u2 = 0; u2 < 2; u2++) \
        _Pragma("unroll") \
        for (int kk = 0; kk < 2; kk++) \
          acc[(mq) * 4 + t2][(nq) * 2 + u2] = __builtin_amdgcn_mfma_f32_16x16x32_bf16( \
              AF[t2][kk], bb[u2][kk], acc[(mq) * 4 + t2][(nq) * 2 + u2], 0, 0, 0); \
    __builtin_amdgcn_s_setprio(0); \
  } while(0)

  // prologue: stage tile 0 into buf0 (stays in flight; gated by vmcnt(8) in t=0)
  STAGE_TILE(0, 0);

  for (int t = 0; t < 32; t++){
    const int bA = (t & 1) ? 32768 : 0;
    const int bB = bA + 16384;
    const int nx = (t & 1) ? 0 : 32768;
    bf16x8 aA[4][2], aB[4][2], bb[2][2];
    // ---- phase 0: issue next prefetch; counted wait for current tile; gate ----
    // t=31 stages a wrapped dummy tile (buffer never read again) to keep the
    // vmcnt immediate constant.
    STAGE_TILE(nx, (long)((t + 1) & 31) * 64);
    asm volatile("s_waitcnt vmcnt(8)" ::: "memory");
    __builtin_amdgcn_sched_barrier(0);
    __builtin_amdgcn_s_barrier();      // all waves see buf cur populated
    LDA(aA, 0);
    LDB(0);
    __builtin_amdgcn_s_barrier();
    MFMA_Q(aA, 0, 0);
    __builtin_amdgcn_s_barrier();
    // ---- phase 1: (m1,n0) ----
    LDA(aB, 1);
    __builtin_amdgcn_s_barrier();
    MFMA_Q(aB, 1, 0);
    __builtin_amdgcn_s_barrier();
    // ---- phase 2: (m1,n1) ----
    LDB(1);
    __builtin_amdgcn_s_barrier();
    MFMA_Q(aB, 1, 1);
    __builtin_amdgcn_s_barrier();
    // ---- phase 3: (m0,n1) ----
    MFMA_Q(aA, 0, 1);
    __builtin_amdgcn_s_barrier();
  }
  // drain the wrapped prefetch before reusing LDS for the epilogue
  asm volatile("s_waitcnt vmcnt(0)" ::: "memory");
  __builtin_amdgcn_sched_barrier(0);
  __syncthreads();

  // ---- epilogue: transposed tile tileT[c][m] in LDS (swizzled), then stores ----
  // chunk'(m,c) = (m>>3) ^ (c&7) ^ ((c>>3)&7);  elem off = c*256 + chunk'*8 + (m&7)
  #pragma unroll
  for (int t2 = 0; t2 < 8; t2++){
    int m0 = wm * 128 + t2 * 16 + q * 4;
    #pragma unroll
    for (int u2 = 0; u2 < 4; u2++){
      int c = wn * 64 + u2 * 16 + l15;
      ushort4 v = make_ushort4(f2bf(acc[t2][u2][0]), f2bf(acc[t2][u2][1]),
                               f2bf(acc[t2][u2][2]), f2bf(acc[t2][u2][3]));
      int sw = ((m0 >> 3) ^ (c & 7) ^ ((c >> 3) & 7));
      *(ushort4*)&lds[c * 256 + (sw << 3) + (m0 & 7)] = v;
    }
  }
  __syncthreads();
  int rr = tid >> 5;          // 0..15
  int ch = tid & 31;          // 16B chunk index (32 per row)
  if (writeT){
    // Ct rows are c: 256 m-elems contiguous, 32 threads x 16B = 512B coalesced
    #pragma unroll
    for (int p = 0; p < 16; p++){
      int r = p * 16 + rr;
      uint4 v = *(const uint4*)&lds[r * 256 + ((ch ^ (r & 7) ^ ((r >> 3) & 7)) << 3)];
      *(uint4*)&Ct[(cBase + r) * 2048 + mBase + ch * 8] = v;
    }
  }
  // Cd rows are m: gather 8 c-column values, pack, coalesced dwordx4
  #pragma unroll
  for (int p = 0; p < 16; p++){
    int m = p * 16 + rr;
    int msw = (m >> 3), ml = m & 7;
    unsigned w[4];
    #pragma unroll
    for (int jj = 0; jj < 4; jj++){
      int c0 = ch * 8 + jj * 2, c1 = c0 + 1;
      unsigned lo = lds[c0 * 256 + (((msw ^ (c0 & 7) ^ (ch & 7)) << 3)) + ml];
      unsigned hi = lds[c1 * 256 + (((msw ^ (c1 & 7) ^ (ch & 7)) << 3)) + ml];
      w[jj] = lo | (hi << 16);
    }
    uint4 v = make_uint4(w[0], w[1], w[2], w[3]);
    *(uint4*)&Cd[(mBase + m) * 12288 + cBase + ch * 8] = v;
  }
#undef STAGE_TILE
#undef LDA
#undef LDB
#undef MFMA_Q
}

// ---------------- K7: out[b,o,n,s] = bias[n,o] + sum_{k,i} Gk[n,(b,i,s)]*W[n,k,i,o] ----------------
// bf16 LDS (25.6KB, 800B/row pad -> 2-way bank alias = free), uint4 16B staging
// loads, in-loop bf16 unpack. ~30KB LDS -> 5 blocks/CU.
__global__ __launch_bounds__(256, 4) void k_final(const u16* __restrict__ G0,
                                                  const u16* __restrict__ G1,
                                                  const u16* __restrict__ G2,
                                                  const float* __restrict__ W,
                                                  const float* __restrict__ biasN,
                                                  float* __restrict__ out){
  __shared__ __align__(16) u16 gs[32 * 400];   // per-b row: 384 bf16 + 16 pad
  __shared__ __align__(16) float ws4[1024];    // W[n][k] slice [i=32][o=32]
  __shared__ float bbuf[32];
  int bid = blockIdx.x;
  int n = (bid & 7) * 256 + (bid >> 3);   // XCD-swizzle: adjacent n share an XCD L2
  int t = threadIdx.x;
  int b = t >> 3, oc = t & 7;
  f32x4 acc[4][3];                         // [jo: o=oc+8*jo][s-quad]
  #pragma unroll
  for (int jo = 0; jo < 4; jo++)
    #pragma unroll
    for (int v = 0; v < 3; v++) acc[jo][v] = (f32x4){0.f, 0.f, 0.f, 0.f};

  const u16* srcs[3] = {G0, G1, G2};
  for (int k = 0; k < 3; k++){
    __syncthreads();
    // stage G[n] slab: 12288 bf16 = 1536 x 16B chunks; 48 chunks per b-row
    const uint4* src = (const uint4*)(srcs[k] + (long)n * 12288);
    #pragma unroll
    for (int p = 0; p < 6; p++){
      int c = t + p * 256;
      int br = c / 48, wi = c - br * 48;
      *(uint4*)&gs[br * 400 + wi * 8] = src[c];
    }
    const float4* wsrc = (const float4*)(W + (long)n * 3072 + k * 1024);
    *(float4*)&ws4[t * 4] = wsrc[t];
    if (k == 0 && t < 8) *(float4*)&bbuf[t * 4] = ((const float4*)(biasN + (long)n * 32))[t];
    __syncthreads();

    const u16* gp = gs + b * 400;
    #pragma unroll 4
    for (int ii = 0; ii < 16; ii++){       // two i per iter: i0=2ii, i1=2ii+1
      uint4 A  = *(const uint4*)&gp[ii * 24];
      uint4 Bc = *(const uint4*)&gp[ii * 24 + 8];
      uint4 Cc = *(const uint4*)&gp[ii * 24 + 16];
      float2 p0 = unp2(A.x),  p1 = unp2(A.y),  p2 = unp2(A.z),  p3 = unp2(A.w);
      float2 p4 = unp2(Bc.x), p5 = unp2(Bc.y), p6 = unp2(Bc.z), p7 = unp2(Bc.w);
      float2 p8 = unp2(Cc.x), p9 = unp2(Cc.y), pa = unp2(Cc.z), pb = unp2(Cc.w);
      f32x4 G0v0 = (f32x4){p0.x, p0.y, p1.x, p1.y};
      f32x4 G0v1 = (f32x4){p2.x, p2.y, p3.x, p3.y};
      f32x4 G0v2 = (f32x4){p4.x, p4.y, p5.x, p5.y};
      f32x4 G1v0 = (f32x4){p6.x, p6.y, p7.x, p7.y};
      f32x4 G1v1 = (f32x4){p8.x, p8.y, p9.x, p9.y};
      f32x4 G1v2 = (f32x4){pa.x, pa.y, pb.x, pb.y};
      #pragma unroll
      for (int jo = 0; jo < 4; jo++){
        float w0 = ws4[(ii * 2)     * 32 + oc + jo * 8];   // broadcast reads
        float w1 = ws4[(ii * 2 + 1) * 32 + oc + jo * 8];
        acc[jo][0] += G0v0 * w0;
        acc[jo][1] += G0v1 * w0;
        acc[jo][2] += G0v2 * w0;
        acc[jo][0] += G1v0 * w1;
        acc[jo][1] += G1v1 * w1;
        acc[jo][2] += G1v2 * w1;
      }
    }
  }
  #pragma unroll
  for (int jo = 0; jo < 4; jo++){
    int o = oc + jo * 8;
    float bv = bbuf[o];
    f32x4 bs = {bv, bv, bv, bv};
    long base = ((long)(b * 32 + o) * 2048 + n) * 12;
    *(f32x4*)(out + base)     = acc[jo][0] + bs;
    *(f32x4*)(out + base + 4) = acc[jo][1] + bs;
    *(f32x4*)(out + base + 8) = acc[jo][2] + bs;
  }
}

extern "C" void kernel_launch(void* const* d_in, const int* in_sizes, int n_in,
                              void* d_out, int out_size, void* d_ws, size_t ws_size,
                              hipStream_t stream){
  const float* x    = (const float*)d_in[0];
  const float* E1   = (const float*)d_in[1];
  const float* E2   = (const float*)d_in[2];
  const float* P1   = (const float*)d_in[3];
  const float* P2   = (const float*)d_in[4];
  const float* BP1  = (const float*)d_in[5];
  const float* BP2  = (const float*)d_in[6];
  const float* fc0w = (const float*)d_in[7];
  const float* fc0b = (const float*)d_in[8];
  const float* fc1w = (const float*)d_in[9];
  const float* fc1b = (const float*)d_in[10];
  const float* fc2w = (const float*)d_in[11];
  const float* fc2b = (const float*)d_in[12];
  float* out = (float*)d_out;

  char* ws = (char*)d_ws;
  size_t off = 0;
  auto carve = [&](size_t bytes) -> char* {
    char* p = ws + off;
    off += (bytes + 255) & ~(size_t)255;
    return p;
  };
  float* h1            = (float*)carve((size_t)65536 * 4);
  float* h2raw         = (float*)carve((size_t)512 * 4);
  float* mmat          = (float*)carve((size_t)256 * 4);
  u16* sup             = (u16*)carve((size_t)2048 * 2048 * 2);
  u16* Xbt             = (u16*)carve((size_t)12288 * 2048 * 2);
  u16* Xb              = (u16*)carve((size_t)2048 * 12288 * 2);
  u16* G1t             = (u16*)carve((size_t)12288 * 2048 * 2);
  u16* G1              = (u16*)carve((size_t)2048 * 12288 * 2);
  float* W             = (float*)carve((size_t)2048 * 3072 * 4);
  float* biasN         = (float*)carve((size_t)2048 * 32 * 4);
  u16* G2              = Xbt;   // alias: Xbt dead after GEMM1, GEMM2 writes G2 here
  (void)ws_size; (void)in_sizes; (void)n_in; (void)out_size;

  k_h1     <<<256, 256, 0, stream>>>(x, fc0w, fc0b, h1);
  k_h2a    <<<512, 256, 0, stream>>>(h1, fc1w, h2raw);
  k_h2b    <<<1, 512, 0, stream>>>(h2raw, fc1b, fc2w, fc2b, mmat);
  k_support<<<2048, 256, 0, stream>>>(E1, E2, mmat, sup);
  k_xbt2   <<<dim3(192, 32), 256, 0, stream>>>(x, Xb, Xbt);
  k_wb2    <<<6400, 256, 0, stream>>>(E1, E2, P1, P2, BP1, BP2, W, biasN);
  k_gemm   <<<dim3(48, 8), 512, 0, stream>>>(sup, Xbt, G1, G1t, 1);   // G1 = S@X
  k_gemm   <<<dim3(48, 8), 512, 0, stream>>>(sup, G1t, G2, G1t, 0);   // G2 = S@G1
  k_final  <<<2048, 256, 0, stream>>>(Xb, G1, G2, W, biasN, out);
}

// Round 3
// 615.754 us; speedup vs baseline: 1.0662x; 1.0662x over previous
//
#include <hip/hip_runtime.h>

// DGCN decomposition:
//   m = MLP(x[0])                       (tiny, fp32)
//   S = softmax(relu(E1 @ m @ E2^T))    (row softmax, fp32 -> bf16)
//   G1 = S @ X, G2 = S @ G1             (bf16 MFMA GEMMs, X = x as [m, (b,i,s)])
//   out[b,o,n,s] = bias[n,o] + sum_{k,i} Gk[n,(b,i,s)] * W[n,k,i,o]
// S^2 is never materialized (saves a 2048^3 GEMM).
//
// R6: k_gemm staging STAGGERED per phase (m196/m201 fine-interleave): phase 0
//   issues B0-B3 of tile t+1, phase 1 issues A0,A2, phase 2 issues A1,A3,
//   phase 3 none. Gate = vmcnt(0) BEFORE new issues at phase 0 (only tile-t's
//   8 old loads in flight there; steady-state wait ~0) + barrier. This smooths
//   the 64KB/tile async LDS-write stream that previously clumped against the
//   per-phase ds_reads (lgkm head-of-line blocking). Everything else as R5.

typedef float  f32x4  __attribute__((ext_vector_type(4)));
typedef __bf16 bf16x8 __attribute__((ext_vector_type(8)));
typedef unsigned short u16;

#define GLOAD16(gp, lp) __builtin_amdgcn_global_load_lds( \
    (const __attribute__((address_space(1))) void*)(gp),  \
    (__attribute__((address_space(3))) void*)(lp), 16, 0, 0)

__device__ __forceinline__ u16 f2bf(float f){
  union { float f; unsigned u; } v; v.f = f;
  unsigned u = v.u;
  u += 0x7fffu + ((u >> 16) & 1u);   // round-to-nearest-even
  return (u16)(u >> 16);
}
__device__ __forceinline__ float bf2f(u16 h){
  union { unsigned u; float f; } v; v.u = ((unsigned)h) << 16;
  return v.f;
}
// unpack one uint (2 packed bf16) -> float2 {lo, hi} (lo = lower address)
__device__ __forceinline__ float2 unp2(unsigned u){
  union { unsigned q; float f; } a, b;
  a.q = u << 16; b.q = u & 0xffff0000u;
  return make_float2(a.f, b.f);
}

// ---------------- K1: h1[i,n] = tanh(x[0,i,n,:] . fc0_w + fc0_b) ----------------
__global__ void k_h1(const float* __restrict__ x, const float* __restrict__ fc0w,
                     const float* __restrict__ fc0b, float* __restrict__ h1){
  int g = blockIdx.x * 256 + threadIdx.x;        // g = i*2048 + n, 65536 total
  const float* xp = x + (long)g * 12;
  float s = fc0b[0];
  #pragma unroll
  for (int j = 0; j < 12; j++) s += xp[j] * fc0w[j];
  h1[g] = tanhf(s);
}

// ---------------- K2a: h2raw[i*16+d] = sum_n h1[i,n]*fc1_w[d,n] ----------------
__global__ __launch_bounds__(256) void k_h2a(const float* __restrict__ h1,
                                             const float* __restrict__ fc1w,
                                             float* __restrict__ h2raw){
  __shared__ float red[4];
  int id = blockIdx.x;                 // 0..511 = i*16+d
  int i = id >> 4, d = id & 15;
  int t = threadIdx.x;
  const float* hp = h1 + i * 2048;
  const float* wp = fc1w + d * 2048;
  float s = 0.f;
  for (int nn = t; nn < 2048; nn += 256) s += hp[nn] * wp[nn];
  for (int off = 32; off > 0; off >>= 1) s += __shfl_down(s, off, 64);
  if ((t & 63) == 0) red[t >> 6] = s;
  __syncthreads();
  if (t == 0) h2raw[id] = red[0] + red[1] + red[2] + red[3];
}

// ---------------- K2b: h2 = tanh(h2raw + fc1_b); m[d,e] = tanh(sum_i h2[i,d]*fc2_w[e,i] + fc2_b[e]) ----------------
__global__ void k_h2b(const float* __restrict__ h2raw, const float* __restrict__ fc1b,
                      const float* __restrict__ fc2w, const float* __restrict__ fc2b,
                      float* __restrict__ mmat){
  __shared__ float h2[512];
  int t = threadIdx.x;                 // 512 threads
  {
    int d = t & 15;
    h2[t] = tanhf(h2raw[t] + fc1b[d]);
  }
  __syncthreads();
  if (t < 256){
    int dd = t >> 4, e = t & 15;
    float s2 = fc2b[e];
    #pragma unroll
    for (int ii = 0; ii < 32; ii++) s2 += h2[ii * 16 + dd] * fc2w[e * 32 + ii];
    mmat[dd * 16 + e] = tanhf(s2);
  }
}

// ---------------- K3: support row n = softmax_j(relu(sum_d' (E1[n]@m)[d'] * E2[j,d'])) -> bf16 ----------------
__global__ __launch_bounds__(256) void k_support(const float* __restrict__ E1,
                                                 const float* __restrict__ E2,
                                                 const float* __restrict__ mmat,
                                                 u16* __restrict__ sup){
  __shared__ float ml[256];
  __shared__ float tv[16];
  __shared__ float red[8];
  int n = blockIdx.x, t = threadIdx.x;
  ml[t] = mmat[t];
  __syncthreads();
  if (t < 16){
    float s = 0.f;
    const float* er = E1 + n * 16;
    #pragma unroll
    for (int d = 0; d < 16; d++) s += er[d] * ml[d * 16 + t];
    tv[t] = s;
  }
  __syncthreads();
  float lmax = -1e30f;
  float lv[8];
  #pragma unroll
  for (int p = 0; p < 8; p++){
    int j = t + p * 256;
    const float* e2 = E2 + j * 16;
    float s = 0.f;
    #pragma unroll
    for (int d = 0; d < 16; d++) s += tv[d] * e2[d];
    s = fmaxf(s, 0.f);                 // relu BEFORE softmax
    lv[p] = s;
    lmax = fmaxf(lmax, s);
  }
  for (int off = 32; off > 0; off >>= 1) lmax = fmaxf(lmax, __shfl_down(lmax, off, 64));
  if ((t & 63) == 0) red[t >> 6] = lmax;
  __syncthreads();
  if (t == 0) red[0] = fmaxf(fmaxf(red[0], red[1]), fmaxf(red[2], red[3]));
  __syncthreads();
  float mx = red[0];
  float lsum = 0.f;
  #pragma unroll
  for (int p = 0; p < 8; p++){ float e = __expf(lv[p] - mx); lv[p] = e; lsum += e; }
  for (int off = 32; off > 0; off >>= 1) lsum += __shfl_down(lsum, off, 64);
  if ((t & 63) == 0) red[4 + (t >> 6)] = lsum;
  __syncthreads();
  if (t == 0) red[4] = red[4] + red[5] + red[6] + red[7];
  __syncthreads();
  float inv = 1.f / red[4];
  #pragma unroll
  for (int p = 0; p < 8; p++) sup[(long)n * 2048 + t + p * 256] = f2bf(lv[p] * inv);
}

// ---------------- K4: fused Xb[m][c]=bf16(x), Xbt[c][m]=Xb[m][c] (reads x once) ----------------
__global__ __launch_bounds__(256) void k_xbt2(const float* __restrict__ x,
                                              u16* __restrict__ Xb,
                                              u16* __restrict__ Xbt){
  __shared__ u16 tile[64][65];
  int cT = blockIdx.x * 64;            // 192 tiles over 12288
  int mT = blockIdx.y * 64;            // 32 tiles over 2048
  int t = threadIdx.x;
  int r = t >> 6, cc = t & 63;
  int cg = cT + cc;
  int bi = cg / 12, s = cg - bi * 12;
  long xoff = (long)bi * 24576 + s;    // x[((bi)*2048 + m)*12 + s]
  #pragma unroll
  for (int p = 0; p < 16; p++){
    int rr = p * 4 + r;
    u16 v = f2bf(x[xoff + (long)(mT + rr) * 12]);
    tile[rr][cc] = v;
    Xb[(long)(mT + rr) * 12288 + cg] = v;
  }
  __syncthreads();
  #pragma unroll
  for (int p = 0; p < 16; p++){
    int rr = p * 4 + r;
    Xbt[(long)(cT + rr) * 2048 + mT + cc] = tile[cc][rr];
  }
}

// ---------------- K6: W[n,k,i,o] via float4 + L1 reuse (4 n per block share P slice) ----------------
__global__ __launch_bounds__(256) void k_wb2(const float* __restrict__ E1, const float* __restrict__ E2,
                                             const float* __restrict__ P1, const float* __restrict__ P2,
                                             const float* __restrict__ BP1, const float* __restrict__ BP2,
                                             float* __restrict__ W, float* __restrict__ biasN){
  int bid = blockIdx.x, t = threadIdx.x;
  if (bid < 6144){
    int nb = bid & 511, rb = bid >> 9;       // 512 n-blocks x 12 r-blocks
    int n = nb * 4 + (t >> 6);
    int r4 = rb * 64 + (t & 63);             // float4 index within 768
    const float* e1 = E1 + n * 16;
    const float* e2 = E2 + n * 16;
    f32x4 s = {0.f, 0.f, 0.f, 0.f};
    #pragma unroll
    for (int d = 0; d < 16; d++){
      f32x4 p1 = *(const f32x4*)(P1 + d * 3072 + r4 * 4);
      f32x4 p2 = *(const f32x4*)(P2 + d * 3072 + r4 * 4);
      s += p1 * e1[d] + p2 * e2[d];
    }
    *(f32x4*)(W + (long)n * 3072 + r4 * 4) = s;
  } else {
    int e = (bid - 6144) * 256 + t;          // 65536 bias outputs
    int n = e >> 5, o = e & 31;
    const float* e1 = E1 + n * 16;
    const float* e2 = E2 + n * 16;
    float s = 0.f;
    #pragma unroll
    for (int d = 0; d < 16; d++) s += e1[d] * BP1[d * 32 + o] + e2[d] * BP2[d * 32 + o];
    biasN[e] = s;
  }
}

// ---------------- GEMM: C[m][c] = sum_k A[m][k] * Bt[c][k]; 256x256 tile, 8 waves ----------------
// Phase-split schedule, BK=64 double buffer. Staging staggered 4/2/2/0 across
// the 4 phases (fine ds_read||G-load||MFMA interleave per m196/m201); gate =
// vmcnt(0) before new issues at phase 0 + barrier (steady-state wait ~0).
// LDS XOR swizzle (T2) via pre-swizzled global source; setprio (T5); bijective
// XCD swizzle (T1). Epilogue: swizzled transposed C-tile in LDS.
__global__ __launch_bounds__(512, 2) void k_gemm(const u16* __restrict__ A,
                                                 const u16* __restrict__ Bt,
                                                 u16* __restrict__ Cd,
                                                 u16* __restrict__ Ct,
                                                 int writeT){
  __shared__ u16 lds[65536];           // 128 KiB: buf0 A[0,16384) B[16384,32768); buf1 +32768
  int tid  = threadIdx.x;
  int wave = tid >> 6, lane = tid & 63;
  int l15 = lane & 15, q = lane >> 4, l7 = l15 & 7;
  int wm = wave >> 2, wn = wave & 3;   // 2 x 4 waves; wave-tile 128(m) x 64(c)

  // bijective XCD swizzle: 8 xcds x 48 slots; 6 consecutive slots share the A panel
  int lin  = blockIdx.y * 48 + blockIdx.x;   // 0..383
  int xcd  = lin & 7;
  int slot = lin >> 3;                 // 0..47
  int yN   = slot / 6;                 // 0..7   (m-tile)
  int xN   = (slot - yN * 6) * 8 + xcd;      // 0..47 (c-tile)
  long mBase = (long)yN * 256;
  long cBase = (long)xN * 256;

  f32x4 acc[8][4];
  #pragma unroll
  for (int t2 = 0; t2 < 8; t2++)
    #pragma unroll
    for (int u2 = 0; u2 < 4; u2++) acc[t2][u2] = (f32x4){0.f, 0.f, 0.f, 0.f};

  // staging: chunk L = j*512 + tid -> LDS (row = L>>3, c_lds = L&7); source chunk
  // is pre-swizzled: cel = (tid&7) ^ ((tid>>3)&7)  (row&7 == (tid>>3)&7 for all j)
  int Lrow = tid >> 3;
  int cel  = (tid & 7) ^ (Lrow & 7);
  const u16* gAp = A  + (mBase + Lrow) * 2048 + cel * 8;
  const u16* gBp = Bt + (cBase + Lrow) * 2048 + cel * 8;

  // region r (64 rows): A at lds[nx + r*4096], B at lds[nx + 16384 + r*4096]
#define GL_A(nx, ko, r) GLOAD16(gAp + (r) * (64 * 2048) + (ko), \
                                lds + (nx) + (r) * 4096 + wave * 512)
#define GL_B(nx, ko, r) GLOAD16(gBp + (r) * (64 * 2048) + (ko), \
                                lds + (nx) + 16384 + (r) * 4096 + wave * 512)

#define LDA(dst, mq) do { \
    _Pragma("unroll") \
    for (int t2 = 0; t2 < 4; t2++){ \
      int row = wm * 128 + ((mq) * 4 + t2) * 16 + l15; \
      _Pragma("unroll") \
      for (int kk = 0; kk < 2; kk++) \
        dst[t2][kk] = *(const bf16x8*)&lds[bA + row * 64 + (((kk << 2) | q) ^ l7) * 8]; \
    } } while(0)

#define LDB(nq) do { \
    _Pragma("unroll") \
    for (int u2 = 0; u2 < 2; u2++){ \
      int row = wn * 64 + ((nq) * 2 + u2) * 16 + l15; \
      _Pragma("unroll") \
      for (int kk = 0; kk < 2; kk++) \
        bb[u2][kk] = *(const bf16x8*)&lds[bB + row * 64 + (((kk << 2) | q) ^ l7) * 8]; \
    } } while(0)

#define MFMA_Q(AF, mq, nq) do { \
    __builtin_amdgcn_s_setprio(1); \
    _Pragma("unroll") \
    for (int t2 = 0; t2 < 4; t2++) \
      _Pragma("unroll") \
      for (int u2 = 0; u2 < 2; u2++) \
        _Pragma("unroll") \
        for (int kk = 0; kk < 2; kk++) \
          acc[(mq) * 4 + t2][(nq) * 2 + u2] = __builtin_amdgcn_mfma_f32_16x16x32_bf16( \
              AF[t2][kk], bb[u2][kk], acc[(mq) * 4 + t2][(nq) * 2 + u2], 0, 0, 0); \
    __builtin_amdgcn_s_setprio(0); \
  } while(0)

  // prologue: stage tile 0 into buf0 (order: B0..B3, A0,A2, A1,A3)
  GL_B(0, 0, 0); GL_B(0, 0, 1); GL_B(0, 0, 2); GL_B(0, 0, 3);
  GL_A(0, 0, 0); GL_A(0, 0, 2); GL_A(0, 0, 1); GL_A(0, 0, 3);

  for (int t = 0; t < 32; t++){
    const int bA = (t & 1) ? 32768 : 0;
    const int bB = bA + 16384;
    const int nx = (t & 1) ? 0 : 32768;
    const long ko = (long)(t + 1) * 64;
    bf16x8 aA[4][2], aB[4][2], bb[2][2];
    // ---- phase 0: gate (only tile-t's 8 loads in flight -> wait ~0);
    //      reads (m0 A-frags + n0 B-frags); prefetch B0-B3 of tile t+1 ----
    asm volatile("s_waitcnt vmcnt(0)" ::: "memory");
    __builtin_amdgcn_s_barrier();      // cross-wave: all waves' loads retired
    LDA(aA, 0);
    LDB(0);
    if (t < 31){ GL_B(nx, ko, 0); GL_B(nx, ko, 1); GL_B(nx, ko, 2); GL_B(nx, ko, 3); }
    __builtin_amdgcn_s_barrier();
    MFMA_Q(aA, 0, 0);
    __builtin_amdgcn_s_barrier();
    // ---- phase 1: (m1,n0); prefetch A0,A2 ----
    LDA(aB, 1);
    if (t < 31){ GL_A(nx, ko, 0); GL_A(nx, ko, 2); }
    __builtin_amdgcn_s_barrier();
    MFMA_Q(aB, 1, 0);
    __builtin_amdgcn_s_barrier();
    // ---- phase 2: (m1,n1); prefetch A1,A3 ----
    LDB(1);
    if (t < 31){ GL_A(nx, ko, 1); GL_A(nx, ko, 3); }
    __builtin_amdgcn_s_barrier();
    MFMA_Q(aB, 1, 1);
    __builtin_amdgcn_s_barrier();
    // ---- phase 3: (m0,n1) ----
    MFMA_Q(aA, 0, 1);
    __builtin_amdgcn_s_barrier();
  }
  // outstanding = 0 here (t=31 issued nothing); belt-and-braces before LDS reuse
  asm volatile("s_waitcnt vmcnt(0)" ::: "memory");
  __syncthreads();

  // ---- epilogue: transposed tile tileT[c][m] in LDS (swizzled), then stores ----
  // chunk'(m,c) = (m>>3) ^ (c&7) ^ ((c>>3)&7);  elem off = c*256 + chunk'*8 + (m&7)
  #pragma unroll
  for (int t2 = 0; t2 < 8; t2++){
    int m0 = wm * 128 + t2 * 16 + q * 4;
    #pragma unroll
    for (int u2 = 0; u2 < 4; u2++){
      int c = wn * 64 + u2 * 16 + l15;
      ushort4 v = make_ushort4(f2bf(acc[t2][u2][0]), f2bf(acc[t2][u2][1]),
                               f2bf(acc[t2][u2][2]), f2bf(acc[t2][u2][3]));
      int sw = ((m0 >> 3) ^ (c & 7) ^ ((c >> 3) & 7));
      *(ushort4*)&lds[c * 256 + (sw << 3) + (m0 & 7)] = v;
    }
  }
  __syncthreads();
  int rr = tid >> 5;          // 0..15
  int ch = tid & 31;          // 16B chunk index (32 per row)
  if (writeT){
    // Ct rows are c: 256 m-elems contiguous, 32 threads x 16B = 512B coalesced
    #pragma unroll
    for (int p = 0; p < 16; p++){
      int r = p * 16 + rr;
      uint4 v = *(const uint4*)&lds[r * 256 + ((ch ^ (r & 7) ^ ((r >> 3) & 7)) << 3)];
      *(uint4*)&Ct[(cBase + r) * 2048 + mBase + ch * 8] = v;
    }
  }
  // Cd rows are m: gather 8 c-column values, pack, coalesced dwordx4
  #pragma unroll
  for (int p = 0; p < 16; p++){
    int m = p * 16 + rr;
    int msw = (m >> 3), ml = m & 7;
    unsigned w[4];
    #pragma unroll
    for (int jj = 0; jj < 4; jj++){
      int c0 = ch * 8 + jj * 2, c1 = c0 + 1;
      unsigned lo = lds[c0 * 256 + (((msw ^ (c0 & 7) ^ (ch & 7)) << 3)) + ml];
      unsigned hi = lds[c1 * 256 + (((msw ^ (c1 & 7) ^ (ch & 7)) << 3)) + ml];
      w[jj] = lo | (hi << 16);
    }
    uint4 v = make_uint4(w[0], w[1], w[2], w[3]);
    *(uint4*)&Cd[(mBase + m) * 12288 + cBase + ch * 8] = v;
  }
#undef GL_A
#undef GL_B
#undef LDA
#undef LDB
#undef MFMA_Q
}

// ---------------- K7: out[b,o,n,s] = bias[n,o] + sum_{k,i} Gk[n,(b,i,s)]*W[n,k,i,o] ----------------
// bf16 LDS (25.6KB, 800B/row pad -> 2-way bank alias = free), uint4 16B staging
// loads, in-loop bf16 unpack. ~30KB LDS -> 5 blocks/CU.
__global__ __launch_bounds__(256, 4) void k_final(const u16* __restrict__ G0,
                                                  const u16* __restrict__ G1,
                                                  const u16* __restrict__ G2,
                                                  const float* __restrict__ W,
                                                  const float* __restrict__ biasN,
                                                  float* __restrict__ out){
  __shared__ __align__(16) u16 gs[32 * 400];   // per-b row: 384 bf16 + 16 pad
  __shared__ __align__(16) float ws4[1024];    // W[n][k] slice [i=32][o=32]
  __shared__ float bbuf[32];
  int bid = blockIdx.x;
  int n = (bid & 7) * 256 + (bid >> 3);   // XCD-swizzle: adjacent n share an XCD L2
  int t = threadIdx.x;
  int b = t >> 3, oc = t & 7;
  f32x4 acc[4][3];                         // [jo: o=oc+8*jo][s-quad]
  #pragma unroll
  for (int jo = 0; jo < 4; jo++)
    #pragma unroll
    for (int v = 0; v < 3; v++) acc[jo][v] = (f32x4){0.f, 0.f, 0.f, 0.f};

  const u16* srcs[3] = {G0, G1, G2};
  for (int k = 0; k < 3; k++){
    __syncthreads();
    // stage G[n] slab: 12288 bf16 = 1536 x 16B chunks; 48 chunks per b-row
    const uint4* src = (const uint4*)(srcs[k] + (long)n * 12288);
    #pragma unroll
    for (int p = 0; p < 6; p++){
      int c = t + p * 256;
      int br = c / 48, wi = c - br * 48;
      *(uint4*)&gs[br * 400 + wi * 8] = src[c];
    }
    const float4* wsrc = (const float4*)(W + (long)n * 3072 + k * 1024);
    *(float4*)&ws4[t * 4] = wsrc[t];
    if (k == 0 && t < 8) *(float4*)&bbuf[t * 4] = ((const float4*)(biasN + (long)n * 32))[t];
    __syncthreads();

    const u16* gp = gs + b * 400;
    #pragma unroll 4
    for (int ii = 0; ii < 16; ii++){       // two i per iter: i0=2ii, i1=2ii+1
      uint4 A  = *(const uint4*)&gp[ii * 24];
      uint4 Bc = *(const uint4*)&gp[ii * 24 + 8];
      uint4 Cc = *(const uint4*)&gp[ii * 24 + 16];
      float2 p0 = unp2(A.x),  p1 = unp2(A.y),  p2 = unp2(A.z),  p3 = unp2(A.w);
      float2 p4 = unp2(Bc.x), p5 = unp2(Bc.y), p6 = unp2(Bc.z), p7 = unp2(Bc.w);
      float2 p8 = unp2(Cc.x), p9 = unp2(Cc.y), pa = unp2(Cc.z), pb = unp2(Cc.w);
      f32x4 G0v0 = (f32x4){p0.x, p0.y, p1.x, p1.y};
      f32x4 G0v1 = (f32x4){p2.x, p2.y, p3.x, p3.y};
      f32x4 G0v2 = (f32x4){p4.x, p4.y, p5.x, p5.y};
      f32x4 G1v0 = (f32x4){p6.x, p6.y, p7.x, p7.y};
      f32x4 G1v1 = (f32x4){p8.x, p8.y, p9.x, p9.y};
      f32x4 G1v2 = (f32x4){pa.x, pa.y, pb.x, pb.y};
      #pragma unroll
      for (int jo = 0; jo < 4; jo++){
        float w0 = ws4[(ii * 2)     * 32 + oc + jo * 8];   // broadcast reads
        float w1 = ws4[(ii * 2 + 1) * 32 + oc + jo * 8];
        acc[jo][0] += G0v0 * w0;
        acc[jo][1] += G0v1 * w0;
        acc[jo][2] += G0v2 * w0;
        acc[jo][0] += G1v0 * w1;
        acc[jo][1] += G1v1 * w1;
        acc[jo][2] += G1v2 * w1;
      }
    }
  }
  #pragma unroll
  for (int jo = 0; jo < 4; jo++){
    int o = oc + jo * 8;
    float bv = bbuf[o];
    f32x4 bs = {bv, bv, bv, bv};
    long base = ((long)(b * 32 + o) * 2048 + n) * 12;
    *(f32x4*)(out + base)     = acc[jo][0] + bs;
    *(f32x4*)(out + base + 4) = acc[jo][1] + bs;
    *(f32x4*)(out + base + 8) = acc[jo][2] + bs;
  }
}

extern "C" void kernel_launch(void* const* d_in, const int* in_sizes, int n_in,
                              void* d_out, int out_size, void* d_ws, size_t ws_size,
                              hipStream_t stream){
  const float* x    = (const float*)d_in[0];
  const float* E1   = (const float*)d_in[1];
  const float* E2   = (const float*)d_in[2];
  const float* P1   = (const float*)d_in[3];
  const float* P2   = (const float*)d_in[4];
  const float* BP1  = (const float*)d_in[5];
  const float* BP2  = (const float*)d_in[6];
  const float* fc0w = (const float*)d_in[7];
  const float* fc0b = (const float*)d_in[8];
  const float* fc1w = (const float*)d_in[9];
  const float* fc1b = (const float*)d_in[10];
  const float* fc2w = (const float*)d_in[11];
  const float* fc2b = (const float*)d_in[12];
  float* out = (float*)d_out;

  char* ws = (char*)d_ws;
  size_t off = 0;
  auto carve = [&](size_t bytes) -> char* {
    char* p = ws + off;
    off += (bytes + 255) & ~(size_t)255;
    return p;
  };
  float* h1            = (float*)carve((size_t)65536 * 4);
  float* h2raw         = (float*)carve((size_t)512 * 4);
  float* mmat          = (float*)carve((size_t)256 * 4);
  u16* sup             = (u16*)carve((size_t)2048 * 2048 * 2);
  u16* Xbt             = (u16*)carve((size_t)12288 * 2048 * 2);
  u16* Xb              = (u16*)carve((size_t)2048 * 12288 * 2);
  u16* G1t             = (u16*)carve((size_t)12288 * 2048 * 2);
  u16* G1              = (u16*)carve((size_t)2048 * 12288 * 2);
  float* W             = (float*)carve((size_t)2048 * 3072 * 4);
  float* biasN         = (float*)carve((size_t)2048 * 32 * 4);
  u16* G2              = Xbt;   // alias: Xbt dead after GEMM1, GEMM2 writes G2 here
  (void)ws_size; (void)in_sizes; (void)n_in; (void)out_size;

  k_h1     <<<256, 256, 0, stream>>>(x, fc0w, fc0b, h1);
  k_h2a    <<<512, 256, 0, stream>>>(h1, fc1w, h2raw);
  k_h2b    <<<1, 512, 0, stream>>>(h2raw, fc1b, fc2w, fc2b, mmat);
  k_support<<<2048, 256, 0, stream>>>(E1, E2, mmat, sup);
  k_xbt2   <<<dim3(192, 32), 256, 0, stream>>>(x, Xb, Xbt);
  k_wb2    <<<6400, 256, 0, stream>>>(E1, E2, P1, P2, BP1, BP2, W, biasN);
  k_gemm   <<<dim3(48, 8), 512, 0, stream>>>(sup, Xbt, G1, G1t, 1);   // G1 = S@X
  k_gemm   <<<dim3(48, 8), 512, 0, stream>>>(sup, G1t, G2, G1t, 0);   // G2 = S@G1
  k_final  <<<2048, 256, 0, stream>>>(Xb, G1, G2, W, biasN, out);
}